// Round 11
// baseline (711.295 us; speedup 1.0000x reference)
//
#include <hip/hip_runtime.h>

typedef unsigned long long u64;
typedef unsigned int u32;

#define KNN 19             // neighbors used (reference k=20 incl. self, minus self)
#define TAU_K 20           // keep 20 incl. self
#define GRES 16            // grid cells per axis (16^3 = 4096 cells)
#define NCELLS (GRES * GRES * GRES)
#define MAXBLK 256         // candidate blocks (F/64); F=16384 -> 256
#define NSCAN 8            // scanner waves per group
#define PR 2               // prime radius: blocks g-PR..g+PR
#define INIT_KEY ((((u64)0x7F800000u) << 32) | 0xFFFFFFFFu)   // (+inf, invalid)

// ---------------------------------------------------------------------------
// Kernel 1: centroids + edges + Morton cell key + cell histogram.
// Centroid/edge math replicates reference op order exactly (contract off).
// ---------------------------------------------------------------------------
__device__ __forceinline__ u32 expand5(u32 x) {
  u32 m = 0;
  m |= (x & 1u);
  m |= (x & 2u) << 2;
  m |= (x & 4u) << 4;
  m |= (x & 8u) << 6;
  m |= (x & 16u) << 8;
  return m;
}

__global__ __launch_bounds__(256) void k_prep(
    const float* __restrict__ verts, const int* __restrict__ faces,
    float4* __restrict__ cent, float4* __restrict__ edges,
    u32* __restrict__ cellkey, u32* __restrict__ hist, int F) {
  #pragma clang fp contract(off)
  int f = blockIdx.x * 256 + threadIdx.x;
  if (f >= F) return;
  int i0 = faces[f * 3 + 0];
  int i1 = faces[f * 3 + 1];
  int i2 = faces[f * 3 + 2];
  float v0x = verts[i0 * 3 + 0], v0y = verts[i0 * 3 + 1], v0z = verts[i0 * 3 + 2];
  float v1x = verts[i1 * 3 + 0], v1y = verts[i1 * 3 + 1], v1z = verts[i1 * 3 + 2];
  float v2x = verts[i2 * 3 + 0], v2y = verts[i2 * 3 + 1], v2z = verts[i2 * 3 + 2];

  float cx = ((v0x + v1x) + v2x) / 3.0f;
  float cy = ((v0y + v1y) + v2y) / 3.0f;
  float cz = ((v0z + v1z) + v2z) / 3.0f;
  cent[f] = make_float4(cx, cy, cz, 0.0f);

  edges[f * 3 + 0] = make_float4(v1x - v0x, v1y - v0y, v1z - v0z, 0.0f);
  edges[f * 3 + 1] = make_float4(v2x - v1x, v2y - v1y, v2z - v1z, 0.0f);
  edges[f * 3 + 2] = make_float4(v0x - v2x, v0y - v2y, v0z - v2z, 0.0f);

  int qx = (int)((cx + 6.0f) * (GRES / 12.0f));
  int qy = (int)((cy + 6.0f) * (GRES / 12.0f));
  int qz = (int)((cz + 6.0f) * (GRES / 12.0f));
  qx = qx < 0 ? 0 : (qx > GRES - 1 ? GRES - 1 : qx);
  qy = qy < 0 ? 0 : (qy > GRES - 1 ? GRES - 1 : qy);
  qz = qz < 0 ? 0 : (qz > GRES - 1 ? GRES - 1 : qz);
  u32 m = expand5((u32)qx) | (expand5((u32)qy) << 1) | (expand5((u32)qz) << 2);
  cellkey[f] = m;
  atomicAdd(&hist[m], 1u);
}

// ---------------------------------------------------------------------------
// Kernel 2: exclusive scan of the cell histogram (one block).
// ---------------------------------------------------------------------------
__global__ __launch_bounds__(1024) void k_scan(
    const u32* __restrict__ hist, u32* __restrict__ cursor) {
  __shared__ u32 sums[1024];
  int t = threadIdx.x;
  int base = t * (NCELLS / 1024);
  u32 s = 0;
  for (int i = 0; i < NCELLS / 1024; ++i) s += hist[base + i];
  sums[t] = s;
  __syncthreads();
  for (int o = 1; o < 1024; o <<= 1) {
    u32 v = (t >= o) ? sums[t - o] : 0u;
    __syncthreads();
    sums[t] += v;
    __syncthreads();
  }
  u32 run = sums[t] - s;
  for (int i = 0; i < NCELLS / 1024; ++i) {
    cursor[base + i] = run;
    run += hist[base + i];
  }
}

// ---------------------------------------------------------------------------
// Kernel 3: scatter into Morton-sorted order. Intra-cell order is atomic-racy
// but the final output depends only on exact (d2, orig-id)-ranked sets, which
// are permutation-invariant -> output deterministic.
// ---------------------------------------------------------------------------
__global__ __launch_bounds__(256) void k_scatter(
    const float4* __restrict__ cent, const u32* __restrict__ cellkey,
    u32* __restrict__ cursor, u32* __restrict__ ids,
    float4* __restrict__ centS, int F) {
  int f = blockIdx.x * 256 + threadIdx.x;
  if (f >= F) return;
  u32 pos = atomicAdd(&cursor[cellkey[f]], 1u);
  ids[pos] = (u32)f;
  centS[pos] = cent[f];
}

// ---------------------------------------------------------------------------
// Kernel 4: per-64-point-block bounding boxes.
// ---------------------------------------------------------------------------
__global__ __launch_bounds__(64) void k_bbox(
    const float4* __restrict__ centS, float4* __restrict__ blo,
    float4* __restrict__ bhi, int F) {
  int b = blockIdx.x;
  int t = threadIdx.x;
  int idx = b * 64 + t;
  bool ok = idx < F;
  float4 v = centS[ok ? idx : 0];
  float lx = ok ? v.x : __builtin_inff(), hx = ok ? v.x : -__builtin_inff();
  float ly = ok ? v.y : __builtin_inff(), hy = ok ? v.y : -__builtin_inff();
  float lz = ok ? v.z : __builtin_inff(), hz = ok ? v.z : -__builtin_inff();
  for (int m = 1; m < 64; m <<= 1) {
    lx = fminf(lx, __shfl_xor(lx, m));
    ly = fminf(ly, __shfl_xor(ly, m));
    lz = fminf(lz, __shfl_xor(lz, m));
    hx = fmaxf(hx, __shfl_xor(hx, m));
    hy = fmaxf(hy, __shfl_xor(hy, m));
    hz = fmaxf(hz, __shfl_xor(hz, m));
  }
  if (t == 0) {
    blo[b] = make_float4(lx, ly, lz, 0.0f);
    bhi[b] = make_float4(hx, hy, hz, 0.0f);
  }
}

// ---------------------------------------------------------------------------
// Kernel 5: ONE-PASS exact kNN. Block = 8 scanner waves x one 64-face group;
// lane = one face; per-lane top-20-incl-self u64 (d2bits<<32|orig_id) keys in
// registers (ALL static indices). Prime: every scanner scans blocks g-2..g+2
// (tight bound from Morton-local candidates). Sweep: scanner s checks only
// blocks (b&7)==s, per-lane bbox min-d2 (conservative *(1-1e-6)) vs running
// L[19] d2, wave vote -> visit. Exact: current 20th-over-subset >= final
// 20th, so pruned blocks cannot hold a top-20 member. Merge: scanners 1..7
// dump lists to LDS; wave 0 inserts with duplicate-key skip (primed blocks
// appear in all lists; keys unique). Write: first 19 non-self entries ==
// reference idx[:,1:] (self's key (0,id): removing it from the (d2,id) order
// reproduces the diag=-inf ordering exactly, ties included).
// ---------------------------------------------------------------------------
__global__ __launch_bounds__(512) void k_knn(
    const float4* __restrict__ centS, const u32* __restrict__ ids,
    const float4* __restrict__ blo, const float4* __restrict__ bhi,
    int* __restrict__ nearest, int F, int nblk) {
  #pragma clang fp contract(off)
  __shared__ float4 s_bb[2 * MAXBLK];                 // 8 KB
  __shared__ u64 s_l[(NSCAN - 1) * TAU_K * 64];       // 71.7 KB

  int lane = threadIdx.x & 63;
  int w    = threadIdx.x >> 6;    // scanner 0..7
  int g    = blockIdx.x;

  for (int i = threadIdx.x; i < nblk; i += 512) {
    s_bb[2 * i]     = blo[i];
    s_bb[2 * i + 1] = bhi[i];
  }
  __syncthreads();

  int myPos = g * 64 + lane;
  bool live = myPos < F;
  float4 me = centS[live ? myPos : 0];
  u32 myId = live ? ids[myPos] : 0xFFFFFFFFu;

  u64 L[TAU_K];
  #pragma unroll
  for (int p = 0; p < TAU_K; ++p) L[p] = INIT_KEY;
  float l19 = __builtin_inff();

  int plo = g - PR; if (plo < 0) plo = 0;
  int phi = g + PR; if (phi > nblk - 1) phi = nblk - 1;

  // PRIME: all scanners scan the 5 Morton-local blocks (incl. own -> self).
  for (int b = plo; b <= phi; ++b) {
    int base = b * 64;
    int cnt = (base + 64 <= F) ? 64 : (F - base);
    #pragma unroll 4
    for (int q = 0; q < cnt; ++q) {
      int jj = base + q;                        // wave-uniform -> broadcast
      float4 cj = centS[jj];
      float dx = me.x - cj.x, dy = me.y - cj.y, dz = me.z - cj.z;
      float d2 = (dx * dx + dy * dy) + dz * dz;   // bit-exact reference form
      u64 key = (((u64)__float_as_uint(d2)) << 32) | (u64)ids[jj];
      if (key < L[TAU_K - 1]) {
        u64 prev = key;
        #pragma unroll
        for (int p = 0; p < TAU_K; ++p) {
          u64 o = L[p];
          L[p] = prev < o ? prev : o;
          prev = key < o ? o : key;
        }
        l19 = __uint_as_float((u32)(L[TAU_K - 1] >> 32));
      }
    }
  }

  // SWEEP: scanner w owns blocks (b & (NSCAN-1)) == w, excluding primed.
  for (int b = w; b < nblk; b += NSCAN) {
    if (b >= plo && b <= phi) continue;
    float4 lo = s_bb[2 * b], hi = s_bb[2 * b + 1];
    float cxx = fminf(fmaxf(me.x, lo.x), hi.x);
    float cyy = fminf(fmaxf(me.y, lo.y), hi.y);
    float czz = fminf(fmaxf(me.z, lo.z), hi.z);
    float ddx = me.x - cxx, ddy = me.y - cyy, ddz = me.z - czz;
    float dmin = ((ddx * ddx + ddy * ddy) + ddz * ddz) * 0.999999f;
    if (__any(live && dmin <= l19)) {
      int base = b * 64;
      int cnt = (base + 64 <= F) ? 64 : (F - base);
      #pragma unroll 4
      for (int q = 0; q < cnt; ++q) {
        int jj = base + q;
        float4 cj = centS[jj];
        float dx = me.x - cj.x, dy = me.y - cj.y, dz = me.z - cj.z;
        float d2 = (dx * dx + dy * dy) + dz * dz;
        u64 key = (((u64)__float_as_uint(d2)) << 32) | (u64)ids[jj];
        if (key < L[TAU_K - 1]) {
          u64 prev = key;
          #pragma unroll
          for (int p = 0; p < TAU_K; ++p) {
            u64 o = L[p];
            L[p] = prev < o ? prev : o;
            prev = key < o ? o : key;
          }
          l19 = __uint_as_float((u32)(L[TAU_K - 1] >> 32));
        }
      }
    }
  }

  // MERGE: scanners 1..7 publish; scanner 0 inserts with dup-skip.
  if (w > 0) {
    #pragma unroll
    for (int p = 0; p < TAU_K; ++p)
      s_l[((w - 1) * TAU_K + p) * 64 + lane] = L[p];
  }
  __syncthreads();

  if (w == 0 && live) {
    for (int s = 0; s < NSCAN - 1; ++s) {
      #pragma unroll
      for (int p = 0; p < TAU_K; ++p) {
        u64 key = s_l[(s * TAU_K + p) * 64 + lane];
        if (key < L[TAU_K - 1]) {
          bool dup = false;
          #pragma unroll
          for (int q = 0; q < TAU_K; ++q) dup = dup || (L[q] == key);
          if (!dup) {
            u64 prev = key;
            #pragma unroll
            for (int q = 0; q < TAU_K; ++q) {
              u64 o = L[q];
              L[q] = prev < o ? prev : o;
              prev = key < o ? o : key;
            }
          }
        }
      }
    }
    int outn = 0;
    int* dst = nearest + (size_t)myId * KNN;
    #pragma unroll
    for (int p = 0; p < TAU_K; ++p) {
      u32 idp = (u32)L[p];
      if (idp != myId && outn < KNN) { dst[outn] = (int)idp; ++outn; }
    }
  }
}

// ---------------------------------------------------------------------------
// Kernel 6: one thread per (face, neighbor): 3x3 segment-pair crossings.
// ---------------------------------------------------------------------------
__global__ __launch_bounds__(256) void k_cross(
    const float4* __restrict__ edges, const int* __restrict__ nearest,
    int* __restrict__ ccbuf, int total) {
  #pragma clang fp contract(off)
  int idx = blockIdx.x * 256 + threadIdx.x;
  if (idx >= total) return;
  int f = idx / KNN;
  int g = nearest[idx];

  float e[3][3], nb[3][3];
  #pragma unroll
  for (int a = 0; a < 3; ++a) {
    float4 t = edges[f * 3 + a];
    e[a][0] = t.x; e[a][1] = t.y; e[a][2] = t.z;
  }
  #pragma unroll
  for (int b = 0; b < 3; ++b) {
    float4 t = edges[g * 3 + b];
    nb[b][0] = t.x; nb[b][1] = t.y; nb[b][2] = t.z;
  }

  int cc = 0;
  #pragma unroll
  for (int a = 0; a < 3; ++a) {
    #pragma unroll
    for (int b = 0; b < 3; ++b) {
      float c0 = e[a][1] * nb[b][2] - e[a][2] * nb[b][1];
      float c1 = e[a][2] * nb[b][0] - e[a][0] * nb[b][2];
      float c2 = e[a][0] * nb[b][1] - e[a][1] * nb[b][0];
      float den = (c0 * e[a][0] + c1 * e[a][1]) + c2 * e[a][2];
      float tn  = (c0 * nb[b][0] + c1 * nb[b][1]) + c2 * nb[b][2];
      float un  = (c0 * e[b][0]  + c1 * e[b][1])  + c2 * e[b][2];
      float t = tn / den;
      float u = un / den;
      if (t >= 0.0f && t <= 1.0f && u >= 0.0f && u <= 1.0f) ++cc;
    }
  }
  ccbuf[idx] = cc;
}

// ---------------------------------------------------------------------------
// Kernel 7: per-face weighted sum, block-reduced.
// ---------------------------------------------------------------------------
__global__ __launch_bounds__(256) void k_wsum(
    const int* __restrict__ ccbuf, const float* __restrict__ probs,
    float* __restrict__ partial, int F) {
  int f = blockIdx.x * 256 + threadIdx.x;
  float w = 0.0f;
  if (f < F) {
    int c = 0;
    #pragma unroll
    for (int s = 0; s < KNN; ++s) c += ccbuf[(size_t)f * KNN + s];
    w = probs[f] * (float)c;
  }
  __shared__ float red[256];
  red[threadIdx.x] = w;
  __syncthreads();
  #pragma unroll
  for (int s = 128; s > 0; s >>= 1) {
    if (threadIdx.x < s) red[threadIdx.x] += red[threadIdx.x + s];
    __syncthreads();
  }
  if (threadIdx.x == 0) partial[blockIdx.x] = red[0];
}

// ---------------------------------------------------------------------------
// Kernel 8: deterministic final reduction; /F exact (F = 2^14)
// ---------------------------------------------------------------------------
__global__ void k_final(const float* __restrict__ partial, float* __restrict__ out,
                        int nblk, float invF) {
  if (threadIdx.x == 0 && blockIdx.x == 0) {
    float s = 0.0f;
    for (int i = 0; i < nblk; ++i) s += partial[i];
    out[0] = s * invF;
  }
}

extern "C" void kernel_launch(void* const* d_in, const int* in_sizes, int n_in,
                              void* d_out, int out_size, void* d_ws, size_t ws_size,
                              hipStream_t stream) {
  const float* verts = (const float*)d_in[0];
  const int*   faces = (const int*)d_in[1];
  const float* probs = (const float*)d_in[2];
  float* out = (float*)d_out;
  const int F = in_sizes[2];            // 16384
  const int total = F * KNN;
  const int nblk64 = (F + 63) / 64;     // 256 groups / candidate blocks

  char* ws = (char*)d_ws;
  size_t off = 0;
  auto take = [&](size_t bytes) { char* p = ws + off; off += (bytes + 255) & ~(size_t)255; return p; };

  float4* cent    = (float4*)take((size_t)F * sizeof(float4));
  float4* edges   = (float4*)take((size_t)F * 3 * sizeof(float4));
  u32*    cellkey = (u32*)   take((size_t)F * sizeof(u32));
  u32*    hist    = (u32*)   take((size_t)NCELLS * sizeof(u32));
  u32*    cursor  = (u32*)   take((size_t)NCELLS * sizeof(u32));
  u32*    ids     = (u32*)   take((size_t)F * sizeof(u32));
  float4* centS   = (float4*)take((size_t)F * sizeof(float4));
  float4* blo     = (float4*)take((size_t)nblk64 * sizeof(float4));
  float4* bhi     = (float4*)take((size_t)nblk64 * sizeof(float4));
  int*    nearest = (int*)   take((size_t)total * sizeof(int));
  int*    ccbuf   = (int*)   take((size_t)total * sizeof(int));
  float*  partial = (float*) take(256 * sizeof(float));

  int nblk256 = (F + 255) / 256;        // 64

  hipMemsetAsync(hist, 0, (size_t)NCELLS * sizeof(u32), stream);
  k_prep   <<<nblk256, 256, 0, stream>>>(verts, faces, cent, edges, cellkey, hist, F);
  k_scan   <<<1, 1024, 0, stream>>>(hist, cursor);
  k_scatter<<<nblk256, 256, 0, stream>>>(cent, cellkey, cursor, ids, centS, F);
  k_bbox   <<<nblk64, 64, 0, stream>>>(centS, blo, bhi, F);
  k_knn    <<<nblk64, 512, 0, stream>>>(centS, ids, blo, bhi, nearest, F, nblk64);
  k_cross  <<<(total + 255) / 256, 256, 0, stream>>>(edges, nearest, ccbuf, total);
  k_wsum   <<<nblk256, 256, 0, stream>>>(ccbuf, probs, partial, F);
  k_final  <<<1, 64, 0, stream>>>(partial, out, nblk256, 1.0f / (float)F);
}